// Round 9
// baseline (220.582 us; speedup 1.0000x reference)
//
#include <hip/hip_runtime.h>
#include <stdint.h>

// Problem constants
#define LDIM 256
#define CDIM 20
#define LC   5120      // L*C
#define NB   1024      // batch
#define BM   256       // i-tile rows
#define BN   256       // batch tile
#define ITOT32 1680    // sum_it (160 - 8*it), it=0..19 : 32-K iters per b-col
// exact identities (BM=256): kstart(it) = 256*it = i0 ; iters32(it) = 160 - 8*it

typedef __attribute__((ext_vector_type(8))) short short8;       // 8 bf16 (4 VGPR)
typedef __attribute__((ext_vector_type(4))) float float4v;      // MFMA acc
typedef __attribute__((ext_vector_type(4))) unsigned int uint4v;
typedef unsigned short ushort_t;

#define TB_BYTES (52428800ull)            // 5120*5120*2
#define XB_BYTES (10485760ull)            // 1024*5120*2
#define WS_NEED  (TB_BYTES + XB_BYTES)

// round-to-nearest-even fp32 -> bf16, packed pair
__device__ inline uint32_t pack_bf16x2(float a, float b) {
    uint32_t ua = __float_as_uint(a);
    uint32_t ub = __float_as_uint(b);
    ua += 0x7fffu + ((ua >> 16) & 1u);
    ub += 0x7fffu + ((ub >> 16) & 1u);
    return (ua >> 16) | (ub & 0xffff0000u);
}

__device__ inline float bf16_to_f32(ushort_t u) {
    return __uint_as_float(((uint32_t)u) << 16);
}

// async global->LDS 16B; lds base wave-uniform (HW: base + lane*16). aux=0
// (R6: NT cpol wrecks staging BW).
__device__ inline void load_lds16(const void* g, void* l) {
    __builtin_amdgcn_global_load_lds(
        (const __attribute__((address_space(1))) uint32_t*)g,
        (__attribute__((address_space(3))) uint32_t*)l, 16, 0, 0);
}

// ---------------------------------------------------------------------------
// Convert pass: T fp32 -> bf16 (cols >= BM-tile kstart only), X fp32 -> bf16,
// fused out[b] = theta0 + dot(theta_lc, x[b,:]).
// ---------------------------------------------------------------------------
__global__ __launch_bounds__(256) void conv_kernel(
    const float* __restrict__ T, const float* __restrict__ X,
    const float* __restrict__ th0, const float* __restrict__ thlc,
    ushort_t* __restrict__ Tb, ushort_t* __restrict__ Xb,
    float* __restrict__ out)
{
    const int bid = blockIdx.x;
    const int t   = threadIdx.x;
    __shared__ float red[4];

    if (bid < LC) {
        const int r  = bid;
        const int tk = (r >> 8) << 8;      // BM=256 tile kstart (exact identity)
        const float*  src = T  + (size_t)r * LC;
        ushort_t*     dst = Tb + (size_t)r * LC;
        for (int c = tk + t * 4; c < LC; c += 1024) {
            float4 f = *(const float4*)(src + c);
            uint2 u;
            u.x = pack_bf16x2(f.x, f.y);
            u.y = pack_bf16x2(f.z, f.w);
            *(uint2*)(dst + c) = u;
        }
    } else {
        const int b = bid - LC;
        const float*  src = X  + (size_t)b * LC;
        ushort_t*     dst = Xb + (size_t)b * LC;
        float s = 0.f;
        for (int c = t * 4; c < LC; c += 1024) {
            float4 f = *(const float4*)(src + c);
            float4 w = *(const float4*)(thlc + c);
            s += f.x * w.x + f.y * w.y + f.z * w.z + f.w * w.w;
            uint2 u;
            u.x = pack_bf16x2(f.x, f.y);
            u.y = pack_bf16x2(f.z, f.w);
            *(uint2*)(dst + c) = u;
        }
        s += __shfl_xor(s, 1);  s += __shfl_xor(s, 2);  s += __shfl_xor(s, 4);
        s += __shfl_xor(s, 8);  s += __shfl_xor(s, 16); s += __shfl_xor(s, 32);
        if ((t & 63) == 0) red[t >> 6] = s;
        __syncthreads();
        if (t == 0) out[b] = th0[0] + red[0] + red[1] + red[2] + red[3];
    }
}

// ---------------------------------------------------------------------------
// Pair kernel v8: software-pipelined K-loop.
//   256x256 tile, 1024 threads (16 waves, wave-tile 64x64, acc 64 VGPR),
//   BK=32 stages, 2 x 32 KB LDS. Per iter: barrier (drains only stage g+1,
//   which had a full MFMA+ds_read in flight) -> issue DMA(g+2) into buf[g&1]
//   (its fragments were consumed before the barrier) -> MFMA(g) from VGPR
//   fragments -> ds_read fragments(g+1). Only one stage outstanding at any
//   barrier, so the vmcnt(0)-before-barrier drain is mostly covered.
//   256 blocks (1/CU), R8-proven decode (kblk bcol-siblings adjacent, same
//   XCD mod 8). Staged bytes: 215 MB (minimum for this tiling).
// ---------------------------------------------------------------------------
__global__ __launch_bounds__(1024, 4) void pair_bf(
    const ushort_t* __restrict__ Tb, const ushort_t* __restrict__ Xb,
    float* __restrict__ out)
{
    const int n    = blockIdx.x;                   // 0..255
    const int kblk = (n & 7) | ((n >> 5) << 3);    // 0..63; siblings n,n+8,n+16,n+24
    const int bn0  = ((n >> 3) & 3) * BN;

    const int gbeg = (ITOT32 * kblk) >> 6;
    const int gend = (ITOT32 * (kblk + 1)) >> 6;

    // locate starting segment: iters32(it) = 160 - 8*it
    int it = 0, pre = 0;
    while (pre + (160 - (it << 3)) <= gbeg) { pre += 160 - (it << 3); ++it; }
    const int li = gbeg - pre;

    // LDS: chunk(row, slot) = row*4 + slot, 16 B/chunk; slot = g ^ swz(row),
    // swz(r) = (r ^ (r>>2)) & 3  -> fragment reads are 2-way bank (free, m136)
    __shared__ __align__(16) ushort_t A_s[2][1024 * 8];   // 2 x 16 KB
    __shared__ __align__(16) ushort_t B_s[2][1024 * 8];   // 2 x 16 KB

    const int t    = threadIdx.x;            // 0..1023
    const int lane = t & 63;
    const int wid  = t >> 6;                 // 0..15
    const int wm   = (wid & 3) * 64;         // wave i-offset
    const int wn   = (wid >> 2) * 64;        // wave b-offset
    const int l16  = lane & 15;
    const int qk   = lane >> 4;              // k-quad (granule) 0..3

    // ---- DMA lane constants: ONE instr per wave per matrix per stage.
    // chunk c = wid*64 + lane; row = c>>2; slot = c&3; granule = slot ^ swz(row)
    const int  cch = (wid << 6) + lane;
    const int  rw  = cch >> 2;
    const int  gA  = (cch & 3) ^ ((rw ^ (rw >> 2)) & 3);
    const uint32_t offA = (uint32_t)rw * LC + (gA << 3);
    const uint32_t offB = (uint32_t)(bn0 + rw) * LC + (gA << 3);
    const int  ldsW = wid << 9;              // wave-uniform LDS base (elements)

    // ---- LDS fragment read byte-addresses (loop-invariant)
    int adrA[4], adrB[4];
    #pragma unroll
    for (int mt = 0; mt < 4; ++mt) {
        const int r = wm + mt * 16 + l16;
        adrA[mt] = ((r << 2) + (qk ^ ((r ^ (r >> 2)) & 3))) << 4;
    }
    #pragma unroll
    for (int nt = 0; nt < 4; ++nt) {
        const int r = wn + nt * 16 + l16;
        adrB[nt] = ((r << 2) + (qk ^ ((r ^ (r >> 2)) & 3))) << 4;
    }

    // ---- issue-side state (runs 2 stages ahead of compute) ----------------
    int itI = it, liI = li;
    uint32_t k0, baseA;
    auto rebaseI = [&]() {
        const uint32_t i0I = itI << 8;
        k0    = i0I + (liI << 5);
        baseA = i0I * LC + k0;
    };
    rebaseI();
    auto issue = [&](int cb) {
        load_lds16(Tb + baseA + offA, A_s[cb] + ldsW);
        load_lds16(Xb + k0   + offB, B_s[cb] + ldsW);
        ++liI;
        if (liI == 160 - (itI << 3)) {
            ++itI; liI = 0;
            if (itI < 20) rebaseI();
        } else { k0 += 32; baseA += 32; }
    };

    float4v acc[4][4];
    #pragma unroll
    for (int mt = 0; mt < 4; ++mt)
        #pragma unroll
        for (int nt = 0; nt < 4; ++nt)
            #pragma unroll
            for (int r = 0; r < 4; ++r) acc[mt][nt][r] = 0.f;

    int itC = it, liC = li;

    // ---- prologue: stage gbeg -> buf0, gbeg+1 -> buf1, read frags(gbeg) ---
    issue(0);
    issue(1);
    __syncthreads();                         // drains both prologue stages
    short8 fa[4], fb[4];
    #pragma unroll
    for (int mt = 0; mt < 4; ++mt)
        fa[mt] = *(const short8*)((const char*)A_s[0] + adrA[mt]);
    #pragma unroll
    for (int nt = 0; nt < 4; ++nt)
        fb[nt] = *(const short8*)((const char*)B_s[0] + adrB[nt]);

    for (int g = gbeg; g < gend; ++g) {
        const int cur = (g - gbeg) & 1;
        __syncthreads();                     // drains DMA(g+1); orders all
                                             // ds_read(g) before issue(g+2)
        if (g + 2 < gend) issue(cur);        // stage g+2 -> buf[cur] (free now)

        // MFMA(g) from register fragments
        #pragma unroll
        for (int mt = 0; mt < 4; ++mt)
            #pragma unroll
            for (int nt = 0; nt < 4; ++nt)
                acc[mt][nt] = __builtin_amdgcn_mfma_f32_16x16x32_bf16(
                    fa[mt], fb[nt], acc[mt][nt], 0, 0, 0);

        // segment boundary: fused epilogue flush
        ++liC;
        const bool segEnd = (liC == 160 - (itC << 3));
        if (segEnd || g + 1 == gend) {
            const int i0 = itC << 8;
            #pragma unroll
            for (int nt = 0; nt < 4; ++nt) {
                const int b = bn0 + wn + nt * 16 + l16;
                const ushort_t* xb = Xb + (size_t)b * LC + i0 + wm + qk * 4;
                float s = 0.f;
                #pragma unroll
                for (int mt = 0; mt < 4; ++mt) {
                    ushort4 xv = *(const ushort4*)(xb + mt * 16);
                    s += acc[mt][nt][0] * bf16_to_f32(xv.x)
                       + acc[mt][nt][1] * bf16_to_f32(xv.y)
                       + acc[mt][nt][2] * bf16_to_f32(xv.z)
                       + acc[mt][nt][3] * bf16_to_f32(xv.w);
                }
                s += __shfl_xor(s, 16);      // reduce the 4 k-quads (same b)
                s += __shfl_xor(s, 32);
                if (qk == 0) atomicAdd(&out[b], s);
            }
            #pragma unroll
            for (int mt = 0; mt < 4; ++mt)
                #pragma unroll
                for (int nt = 0; nt < 4; ++nt)
                    #pragma unroll
                    for (int r = 0; r < 4; ++r) acc[mt][nt][r] = 0.f;
        }
        if (segEnd) { ++itC; liC = 0; }

        // ds_read fragments for stage g+1 (landed at this iter's barrier)
        if (g + 1 < gend) {
            const char* As = (const char*)A_s[cur ^ 1];
            const char* Bs = (const char*)B_s[cur ^ 1];
            #pragma unroll
            for (int mt = 0; mt < 4; ++mt)
                fa[mt] = *(const short8*)(As + adrA[mt]);
            #pragma unroll
            for (int nt = 0; nt < 4; ++nt)
                fb[nt] = *(const short8*)(Bs + adrB[nt]);
        }
    }
}

// ===========================================================================
// Fallback (ws too small): proven R2 path, fp32 staging from global.
// ===========================================================================
__global__ __launch_bounds__(256) void init_kernel(
    const float* __restrict__ x, const float* __restrict__ th0,
    const float* __restrict__ thlc, float* __restrict__ out)
{
    const int b = blockIdx.x;
    const float4* xb = (const float4*)(x + (size_t)b * LC);
    const float4* tv = (const float4*)thlc;
    float s = 0.f;
    for (int i = threadIdx.x; i < LC / 4; i += 256) {
        float4 a = xb[i], t = tv[i];
        s += a.x * t.x + a.y * t.y + a.z * t.z + a.w * t.w;
    }
    s += __shfl_xor(s, 1);  s += __shfl_xor(s, 2);  s += __shfl_xor(s, 4);
    s += __shfl_xor(s, 8);  s += __shfl_xor(s, 16); s += __shfl_xor(s, 32);
    __shared__ float red[4];
    if ((threadIdx.x & 63) == 0) red[threadIdx.x >> 6] = s;
    __syncthreads();
    if (threadIdx.x == 0) out[b] = th0[0] + red[0] + red[1] + red[2] + red[3];
}

__global__ __launch_bounds__(256) void pair_kernel(
    const float* __restrict__ T, const float* __restrict__ X,
    float* __restrict__ out)
{
    const int n  = blockIdx.x;
    const int r  = n & 7;
    const int g  = n >> 3;
    const int i0  = (g >> 3) * 128;
    const int bn0 = (g & 7) * 128;
    const int kstart = i0;
    const int nIter  = (LC - kstart) >> 6;
    const int ipc    = (nIter + 7) >> 3;
    const int itBeg  = r * ipc;
    const int itEnd  = (itBeg + ipc < nIter) ? (itBeg + ipc) : nIter;
    if (itBeg >= itEnd) return;
    const int kbeg   = kstart + (itBeg << 6);

    __shared__ __align__(16) short A_s[8 * 128 * 8];
    __shared__ __align__(16) short B_s[8 * 128 * 8];

    const int t    = threadIdx.x;
    const int lane = t & 63;
    const int wid  = t >> 6;
    const int wm   = (wid >> 1) * 64;
    const int wn   = (wid & 1) * 64;
    const int l16  = lane & 15;
    const int qk   = lane >> 4;

    const float* pA[4]; const float* pB[4]; int sIdx[4];
    #pragma unroll
    for (int u = 0; u < 4; ++u) {
        const int id  = t + u * 256;
        const int row = id >> 3;
        const int kq  = id & 7;
        pA[u] = T + (size_t)(i0 + row) * LC + kbeg + kq * 8;
        pB[u] = X + (size_t)(bn0 + row) * LC + kbeg + kq * 8;
        sIdx[u] = (kq * 128 + (row ^ kq)) * 8;
    }

    float4v acc[4][4] = {};
    for (int itr = itBeg; itr < itEnd; ++itr) {
        __syncthreads();
        #pragma unroll
        for (int u = 0; u < 4; ++u) {
            float4 a0 = ((const float4*)pA[u])[0];
            float4 a1 = ((const float4*)pA[u])[1];
            float4 b0 = ((const float4*)pB[u])[0];
            float4 b1 = ((const float4*)pB[u])[1];
            pA[u] += 64; pB[u] += 64;
            uint4v va, vb;
            va[0] = pack_bf16x2(a0.x, a0.y); va[1] = pack_bf16x2(a0.z, a0.w);
            va[2] = pack_bf16x2(a1.x, a1.y); va[3] = pack_bf16x2(a1.z, a1.w);
            vb[0] = pack_bf16x2(b0.x, b0.y); vb[1] = pack_bf16x2(b0.z, b0.w);
            vb[2] = pack_bf16x2(b1.x, b1.y); vb[3] = pack_bf16x2(b1.z, b1.w);
            *(uint4v*)(A_s + sIdx[u]) = va;
            *(uint4v*)(B_s + sIdx[u]) = vb;
        }
        __syncthreads();
        #pragma unroll
        for (int step = 0; step < 2; ++step) {
            const int kf = step * 4 + qk;
            short8 af[4], bfr[4];
            #pragma unroll
            for (int mt = 0; mt < 4; ++mt)
                af[mt] = *(const short8*)(A_s + (kf * 128 + ((wm + mt * 16 + l16) ^ kf)) * 8);
            #pragma unroll
            for (int nt = 0; nt < 4; ++nt)
                bfr[nt] = *(const short8*)(B_s + (kf * 128 + ((wn + nt * 16 + l16) ^ kf)) * 8);
            #pragma unroll
            for (int mt = 0; mt < 4; ++mt)
                #pragma unroll
                for (int nt = 0; nt < 4; ++nt)
                    acc[mt][nt] = __builtin_amdgcn_mfma_f32_16x16x32_bf16(
                        af[mt], bfr[nt], acc[mt][nt], 0, 0, 0);
        }
    }
    #pragma unroll
    for (int nt = 0; nt < 4; ++nt) {
        const int b = bn0 + wn + nt * 16 + l16;
        const float* xb = X + (size_t)b * LC + i0 + wm + qk * 4;
        float s = 0.f;
        #pragma unroll
        for (int mt = 0; mt < 4; ++mt) {
            float4 xv = *(const float4*)(xb + mt * 16);
            s += acc[mt][nt][0] * xv.x + acc[mt][nt][1] * xv.y +
                 acc[mt][nt][2] * xv.z + acc[mt][nt][3] * xv.w;
        }
        s += __shfl_xor(s, 16);
        s += __shfl_xor(s, 32);
        if (qk == 0) atomicAdd(&out[b], s);
    }
}

extern "C" void kernel_launch(void* const* d_in, const int* in_sizes, int n_in,
                              void* d_out, int out_size, void* d_ws, size_t ws_size,
                              hipStream_t stream) {
    const float* x    = (const float*)d_in[0];   // (B, L, C) fp32
    const float* th0  = (const float*)d_in[1];   // (1,)
    const float* thlc = (const float*)d_in[2];   // (1, L, C)
    const float* T    = (const float*)d_in[3];   // (1, L, C, L, C) — pre-masked
    float* out = (float*)d_out;                  // (B, 1) fp32

    if (ws_size >= WS_NEED) {
        ushort_t* Tb = (ushort_t*)d_ws;
        ushort_t* Xb = (ushort_t*)((char*)d_ws + TB_BYTES);
        conv_kernel<<<LC + NB, 256, 0, stream>>>(T, x, th0, thlc, Tb, Xb, out);
        pair_bf<<<256, 1024, 0, stream>>>(Tb, Xb, out);
    } else {
        init_kernel<<<NB, 256, 0, stream>>>(x, th0, thlc, out);
        pair_kernel<<<(LC / 128) * (NB / 128) * 8, 256, 0, stream>>>(T, x, out);
    }
}